// Round 9
// baseline (261.798 us; speedup 1.0000x reference)
//
#include <hip/hip_runtime.h>

#define HW 16384
#define C_IN 256
#define C_MID 128
#define C_OUT 32
#define EPSF 1e-5f

typedef __bf16 bf16x8 __attribute__((ext_vector_type(8)));
typedef __bf16 bf16x4 __attribute__((ext_vector_type(4)));
typedef float f32x4 __attribute__((ext_vector_type(4)));

// ---------------- Kernel 1: per-(b,c) stats, nontemporal loads ----------
// 2048 blocks x 512 thr. Same as r8 but all loads are NT (no L2/L3 allocate)
// to test the fill/alloc-serialization theory of the 1.4 TB/s miss-stream cap.
__global__ __launch_bounds__(512) void k_stats6(const float* __restrict__ content,
                                                const float* __restrict__ style,
                                                float* __restrict__ cmean,
                                                float* __restrict__ crstd,
                                                float* __restrict__ smean) {
    const int bc = blockIdx.x;          // 0..2047
    const int t = threadIdx.x;          // 0..511
    const f32x4* cp = (const f32x4*)(content + (size_t)bc * HW);
    const f32x4* sp = (const f32x4*)(style + (size_t)bc * HW);
    const int phase = (bc * 257) & 4095;

    f32x4 c0 = __builtin_nontemporal_load(cp + ((phase + t          ) & 4095));
    f32x4 c1 = __builtin_nontemporal_load(cp + ((phase + t +  1*512) & 4095));
    f32x4 c2 = __builtin_nontemporal_load(cp + ((phase + t +  2*512) & 4095));
    f32x4 c3 = __builtin_nontemporal_load(cp + ((phase + t +  3*512) & 4095));
    f32x4 c4 = __builtin_nontemporal_load(cp + ((phase + t +  4*512) & 4095));
    f32x4 c5 = __builtin_nontemporal_load(cp + ((phase + t +  5*512) & 4095));
    f32x4 c6 = __builtin_nontemporal_load(cp + ((phase + t +  6*512) & 4095));
    f32x4 c7 = __builtin_nontemporal_load(cp + ((phase + t +  7*512) & 4095));
    f32x4 s0 = __builtin_nontemporal_load(sp + ((phase + t          ) & 4095));
    f32x4 s1 = __builtin_nontemporal_load(sp + ((phase + t +  1*512) & 4095));
    f32x4 s2 = __builtin_nontemporal_load(sp + ((phase + t +  2*512) & 4095));
    f32x4 s3 = __builtin_nontemporal_load(sp + ((phase + t +  3*512) & 4095));
    f32x4 s4 = __builtin_nontemporal_load(sp + ((phase + t +  4*512) & 4095));
    f32x4 s5 = __builtin_nontemporal_load(sp + ((phase + t +  5*512) & 4095));
    f32x4 s6 = __builtin_nontemporal_load(sp + ((phase + t +  6*512) & 4095));
    f32x4 s7 = __builtin_nontemporal_load(sp + ((phase + t +  7*512) & 4095));
    asm volatile("" ::
        "v"(c0), "v"(c1), "v"(c2), "v"(c3), "v"(c4), "v"(c5), "v"(c6), "v"(c7),
        "v"(s0), "v"(s1), "v"(s2), "v"(s3), "v"(s4), "v"(s5), "v"(s6), "v"(s7));

    float cs, cq, ss;
    {
        f32x4 a01 = c0 + c1, a23 = c2 + c3, a45 = c4 + c5, a67 = c6 + c7;
        f32x4 a = (a01 + a23) + (a45 + a67);
        cs = (a[0] + a[1]) + (a[2] + a[3]);
        f32x4 q01 = c0 * c0 + c1 * c1, q23 = c2 * c2 + c3 * c3;
        f32x4 q45 = c4 * c4 + c5 * c5, q67 = c6 * c6 + c7 * c7;
        f32x4 q = (q01 + q23) + (q45 + q67);
        cq = (q[0] + q[1]) + (q[2] + q[3]);
        f32x4 b01 = s0 + s1, b23 = s2 + s3, b45 = s4 + s5, b67 = s6 + s7;
        f32x4 bsum = (b01 + b23) + (b45 + b67);
        ss = (bsum[0] + bsum[1]) + (bsum[2] + bsum[3]);
    }

    #pragma unroll
    for (int d = 32; d > 0; d >>= 1) {
        cs += __shfl_xor(cs, d, 64);
        cq += __shfl_xor(cq, d, 64);
        ss += __shfl_xor(ss, d, 64);
    }
    __shared__ float rs[8], rq[8], rss[8];
    const int wv = t >> 6;
    if ((t & 63) == 0) { rs[wv] = cs; rq[wv] = cq; rss[wv] = ss; }
    __syncthreads();
    if (t == 0) {
        float S = 0.f, Q = 0.f, SS = 0.f;
        #pragma unroll
        for (int i = 0; i < 8; ++i) { S += rs[i]; Q += rq[i]; SS += rss[i]; }
        float n = (float)HW;
        float var = (Q - S * S / n) / (n - 1.f);
        cmean[bc] = S / n;
        crstd[bc] = 1.f / sqrtf(var + EPSF);
        smean[bc] = SS / n;
    }
}

// ---------------- Prep: fold norm into conv1 weights (bf16) ----------------
__global__ __launch_bounds__(256) void k_wprep(const float* __restrict__ w1,
                                               const float* __restrict__ b1,
                                               const float* __restrict__ cmean,
                                               const float* __restrict__ crstd,
                                               const float* __restrict__ smean,
                                               __bf16* __restrict__ W1c,
                                               float* __restrict__ bias1c,
                                               __bf16* __restrict__ W1s,
                                               float* __restrict__ bias1s) {
    int o = blockIdx.x, b = blockIdx.y, t = threadIdx.x;
    float w = w1[o * 256 + t];
    float r = crstd[b * 256 + t];
    float wc = w * r;
    W1c[((size_t)(b * 128 + o)) * 256 + t] = (__bf16)wc;
    if (b == 0) W1s[o * 256 + t] = (__bf16)w;
    float pc = wc * cmean[b * 256 + t];
    float ps = w * smean[b * 256 + t];
    __shared__ float rA[256], rB[256];
    rA[t] = pc; rB[t] = ps;
    __syncthreads();
    for (int off = 128; off > 0; off >>= 1) {
        if (t < off) { rA[t] += rA[t + off]; rB[t] += rB[t + off]; }
        __syncthreads();
    }
    if (t == 0) {
        bias1c[b * 128 + o] = b1[o] - rA[0];
        bias1s[b * 128 + o] = b1[o] - rB[0];
    }
}

__global__ __launch_bounds__(256) void k_w2prep(const float* __restrict__ w2,
                                                __bf16* __restrict__ W2b) {
    int i = blockIdx.x * 256 + threadIdx.x;   // 4096 total
    if (i < 4096) W2b[i] = (__bf16)w2[i];
}

// ---------------- Kernel 2: MFMA fused net ----------------
__global__ __launch_bounds__(256) void k_net_mfma(const float* __restrict__ x,
                                                  const __bf16* __restrict__ W1,
                                                  const float* __restrict__ bias1,
                                                  const __bf16* __restrict__ W2,
                                                  const float* __restrict__ b2,
                                                  float* __restrict__ outF,
                                                  int w1_per_batch) {
    __shared__ __bf16 Xl[64 * 256];   // 32 KB, [p][c] swizzled
    __shared__ __bf16 Tl[64 * 128];   // 16 KB, [p][o] swizzled
    const int tid = threadIdx.x;
    const int l = tid & 63, wv = tid >> 6;
    const int lr = l & 15, g = l >> 4;
    const int sw = (lr & 7) << 4;
    const int p0 = blockIdx.x * 64;
    const int b = blockIdx.y;
    const float* xb = x + (size_t)b * C_IN * HW;

    {
        const int p = wv * 16 + lr;
        const float* xp = xb + p0 + p;
        char* row = (char*)&Xl[p * 256];
        #pragma unroll 4
        for (int cc = 0; cc < 16; ++cc) {
            const int c = cc * 16 + g * 4;
            float f0 = xp[(size_t)(c + 0) * HW];
            float f1 = xp[(size_t)(c + 1) * HW];
            float f2 = xp[(size_t)(c + 2) * HW];
            float f3 = xp[(size_t)(c + 3) * HW];
            bf16x4 v;
            v[0] = (__bf16)f0; v[1] = (__bf16)f1; v[2] = (__bf16)f2; v[3] = (__bf16)f3;
            *(bf16x4*)(row + ((c * 2) ^ sw)) = v;
        }
    }
    __syncthreads();

    const f32x4 zero4 = {0.f, 0.f, 0.f, 0.f};
    f32x4 acc[2][4];
    #pragma unroll
    for (int mt = 0; mt < 2; ++mt)
        #pragma unroll
        for (int nt = 0; nt < 4; ++nt) acc[mt][nt] = zero4;

    const __bf16* W1b = W1 + (w1_per_batch ? ((size_t)b << 15) : 0);
    const __bf16* wrow0 = W1b + (size_t)(wv * 32 + lr) * 256 + g * 8;
    const __bf16* wrow1 = wrow0 + 16 * 256;

    #pragma unroll
    for (int kt = 0; kt < 8; ++kt) {
        bf16x8 a0 = *(const bf16x8*)(wrow0 + kt * 32);
        bf16x8 a1 = *(const bf16x8*)(wrow1 + kt * 32);
        #pragma unroll
        for (int nt = 0; nt < 4; ++nt) {
            const char* xrow = (const char*)&Xl[(nt * 16 + lr) * 256];
            bf16x8 bfr = *(const bf16x8*)(xrow + (((kt * 32 + g * 8) * 2) ^ sw));
            acc[0][nt] = __builtin_amdgcn_mfma_f32_16x16x32_bf16(a0, bfr, acc[0][nt], 0, 0, 0);
            acc[1][nt] = __builtin_amdgcn_mfma_f32_16x16x32_bf16(a1, bfr, acc[1][nt], 0, 0, 0);
        }
    }

    float4 bia[2];
    bia[0] = *(const float4*)&bias1[b * 128 + wv * 32 + g * 4];
    bia[1] = *(const float4*)&bias1[b * 128 + wv * 32 + 16 + g * 4];
    #pragma unroll
    for (int mt = 0; mt < 2; ++mt) {
        #pragma unroll
        for (int nt = 0; nt < 4; ++nt) {
            const int p = nt * 16 + lr;
            char* trow = (char*)&Tl[p * 128];
            const int ob = (wv * 32 + mt * 16 + g * 4) * 2;
            bf16x4 tv;
            tv[0] = (__bf16)fmaxf(acc[mt][nt][0] + bia[mt].x, 0.f);
            tv[1] = (__bf16)fmaxf(acc[mt][nt][1] + bia[mt].y, 0.f);
            tv[2] = (__bf16)fmaxf(acc[mt][nt][2] + bia[mt].z, 0.f);
            tv[3] = (__bf16)fmaxf(acc[mt][nt][3] + bia[mt].w, 0.f);
            *(bf16x4*)(trow + (ob ^ sw)) = tv;
        }
    }
    __syncthreads();

    f32x4 acc2[2];
    acc2[0] = zero4; acc2[1] = zero4;
    const int p = wv * 16 + lr;
    const char* trow = (const char*)&Tl[p * 128];
    const __bf16* w2r0 = W2 + (size_t)lr * 128 + g * 8;
    const __bf16* w2r1 = w2r0 + 16 * 128;
    #pragma unroll
    for (int kt = 0; kt < 4; ++kt) {
        bf16x8 bfr = *(const bf16x8*)(trow + (((kt * 32 + g * 8) * 2) ^ sw));
        bf16x8 a0 = *(const bf16x8*)(w2r0 + kt * 32);
        bf16x8 a1 = *(const bf16x8*)(w2r1 + kt * 32);
        acc2[0] = __builtin_amdgcn_mfma_f32_16x16x32_bf16(a0, bfr, acc2[0], 0, 0, 0);
        acc2[1] = __builtin_amdgcn_mfma_f32_16x16x32_bf16(a1, bfr, acc2[1], 0, 0, 0);
    }
    float4 bb0 = *(const float4*)&b2[g * 4];
    float4 bb1 = *(const float4*)&b2[16 + g * 4];
    float* ob = outF + (size_t)b * C_OUT * HW + p0 + p;
    const int o0 = g * 4;
    ob[(size_t)(o0 + 0) * HW] = acc2[0][0] + bb0.x;
    ob[(size_t)(o0 + 1) * HW] = acc2[0][1] + bb0.y;
    ob[(size_t)(o0 + 2) * HW] = acc2[0][2] + bb0.z;
    ob[(size_t)(o0 + 3) * HW] = acc2[0][3] + bb0.w;
    ob[(size_t)(16 + o0 + 0) * HW] = acc2[1][0] + bb1.x;
    ob[(size_t)(16 + o0 + 1) * HW] = acc2[1][1] + bb1.y;
    ob[(size_t)(16 + o0 + 2) * HW] = acc2[1][2] + bb1.z;
    ob[(size_t)(16 + o0 + 3) * HW] = acc2[1][3] + bb1.w;
}

// ---------------- Kernel 3: partial gram of sF ----------
__global__ __launch_bounds__(256) void k_gram(const float* __restrict__ sF,
                                              float* __restrict__ partial) {
    __shared__ float sS[32 * 257];
    int b = blockIdx.y, sl = blockIdx.x;
    int t = threadIdx.x;
    const float* base = sF + (size_t)b * C_OUT * HW + sl * 1024;
    int i = t >> 3, jb = (t & 7) * 4;
    float acc[4] = {0.f, 0.f, 0.f, 0.f};
    for (int ch = 0; ch < 4; ++ch) {
        __syncthreads();
        #pragma unroll
        for (int r = 0; r < 32; ++r)
            sS[r * 257 + t] = base[(size_t)r * HW + ch * 256 + t];
        __syncthreads();
        for (int n = 0; n < 256; ++n) {
            float si = sS[i * 257 + n];
            #pragma unroll
            for (int q = 0; q < 4; ++q)
                acc[q] = fmaf(si, sS[(jb + q) * 257 + n], acc[q]);
        }
    }
    float* dst = partial + ((size_t)(b * 16 + sl)) * 1024 + t * 4;
    #pragma unroll
    for (int q = 0; q < 4; ++q) dst[q] = acc[q];
}

// ---------------- Kernel 4: reduce partials + softmax + scale ----------
__global__ __launch_bounds__(1024) void k_softmax(const float* __restrict__ partial,
                                                  float* __restrict__ scov) {
    int b = blockIdx.x;
    int j = threadIdx.x, i = threadIdx.y;
    float v = 0.f;
    #pragma unroll
    for (int s = 0; s < 16; ++s)
        v += partial[((size_t)(b * 16 + s)) * 1024 + i * 32 + j];
    v *= (1.f / (float)HW);
    float m = v;
    #pragma unroll
    for (int d = 16; d > 0; d >>= 1) m = fmaxf(m, __shfl_xor(m, d, 32));
    float e = expf(v - m);
    float sum = e;
    #pragma unroll
    for (int d = 16; d > 0; d >>= 1) sum += __shfl_xor(sum, d, 32);
    scov[(size_t)b * 1024 + i * 32 + j] = e / sum * 0.17677669529663687f;
}

// ---------------- Kernel 5: out = wu@(scov@cF) + bu + smean + content ----
__global__ __launch_bounds__(256) void k_final(const float* __restrict__ cF,
                                               const float* __restrict__ scov,
                                               const float* __restrict__ wu,
                                               const float* __restrict__ bu,
                                               const float* __restrict__ smean,
                                               const float* __restrict__ content,
                                               float* __restrict__ out) {
    __shared__ float sCov[1024];
    __shared__ float sC[32 * 64];
    __shared__ float sG[32 * 64];
    __shared__ float sWu[32 * 260];
    int t = threadIdx.x;
    int p0 = blockIdx.x * 64;
    int b = blockIdx.y;
    #pragma unroll
    for (int q = 0; q < 4; ++q) sCov[t + 256 * q] = scov[(size_t)b * 1024 + t + 256 * q];
    {
        int p = t & 63, rb = t >> 6;
        #pragma unroll
        for (int pass = 0; pass < 8; ++pass) {
            int r = pass * 4 + rb;
            sC[r * 64 + p] = cF[(size_t)b * C_OUT * HW + (size_t)r * HW + p0 + p];
        }
    }
    {
        int k = t & 31, ob = t >> 5;
        #pragma unroll
        for (int pass = 0; pass < 32; ++pass) {
            int o = pass * 8 + ob;
            sWu[k * 260 + o] = wu[o * 32 + k];
        }
    }
    __syncthreads();
    {
        int gp = t & 63, gib = (t >> 6) * 8;
        #pragma unroll
        for (int rr = 0; rr < 8; ++rr) {
            int gi = gib + rr;
            float a = 0.f;
            #pragma unroll
            for (int k = 0; k < 32; ++k)
                a = fmaf(sCov[gi * 32 + k], sC[k * 64 + gp], a);
            sG[gi * 64 + gp] = a;
        }
    }
    __syncthreads();
    int tx = t & 7, ty = t >> 3;
    float acc[8][8];
    #pragma unroll
    for (int i = 0; i < 8; ++i)
        #pragma unroll
        for (int j = 0; j < 8; ++j) acc[i][j] = 0.f;
    #pragma unroll 4
    for (int k = 0; k < 32; ++k) {
        float4 a4a = *(const float4*)&sWu[k * 260 + ty * 8];
        float4 a4b = *(const float4*)&sWu[k * 260 + ty * 8 + 4];
        float4 b4a = *(const float4*)&sG[k * 64 + tx * 8];
        float4 b4b = *(const float4*)&sG[k * 64 + tx * 8 + 4];
        float a[8] = {a4a.x, a4a.y, a4a.z, a4a.w, a4b.x, a4b.y, a4b.z, a4b.w};
        float bb[8] = {b4a.x, b4a.y, b4a.z, b4a.w, b4b.x, b4b.y, b4b.z, b4b.w};
        #pragma unroll
        for (int i = 0; i < 8; ++i)
            #pragma unroll
            for (int j = 0; j < 8; ++j)
                acc[i][j] = fmaf(a[i], bb[j], acc[i][j]);
    }
    #pragma unroll
    for (int i = 0; i < 8; ++i) {
        int o = ty * 8 + i;
        float add = bu[o] + smean[b * 256 + o];
        const float* csrc = content + (size_t)b * C_IN * HW + (size_t)o * HW + p0 + tx * 8;
        float* dst = out + (size_t)b * C_IN * HW + (size_t)o * HW + p0 + tx * 8;
        float4 c0 = *(const float4*)csrc;
        float4 c1 = *(const float4*)(csrc + 4);
        f32x4 r0 = {acc[i][0] + add + c0.x, acc[i][1] + add + c0.y,
                    acc[i][2] + add + c0.z, acc[i][3] + add + c0.w};
        f32x4 r1 = {acc[i][4] + add + c1.x, acc[i][5] + add + c1.y,
                    acc[i][6] + add + c1.z, acc[i][7] + add + c1.w};
        __builtin_nontemporal_store(r0, (f32x4*)dst);
        __builtin_nontemporal_store(r1, (f32x4*)(dst + 4));
    }
}

extern "C" void kernel_launch(void* const* d_in, const int* in_sizes, int n_in,
                              void* d_out, int out_size, void* d_ws, size_t ws_size,
                              hipStream_t stream) {
    const float* content = (const float*)d_in[0];
    const float* style   = (const float*)d_in[1];
    const float* w1      = (const float*)d_in[2];
    const float* b1      = (const float*)d_in[3];
    const float* w2      = (const float*)d_in[4];
    const float* b2      = (const float*)d_in[5];
    const float* wu      = (const float*)d_in[6];
    const float* bu      = (const float*)d_in[7];
    float* out = (float*)d_out;
    float* ws  = (float*)d_ws;

    float* cmean   = ws;                         // 2048
    float* crstd   = ws + 2048;                  // 2048
    float* smean   = ws + 4096;                  // 2048
    float* scov    = ws + 6144;                  // 8192 (live: softmax->final)
    __bf16* W2b    = (__bf16*)(ws + 6144);       // 4096 bf16 (dead before scov written)
    float* bias1c  = ws + 8192;                  // 1024
    float* bias1s  = ws + 9216;                  // 1024
    float* partial = ws + 14336;                 // 131072 (live: gram->softmax)
    __bf16* W1c    = (__bf16*)(ws + 14336);      // 262144 bf16 (dead before partial written)
    __bf16* W1s    = (__bf16*)(ws + 145408);     // 32768 bf16
    float* cF      = ws + 161792;                // 4194304
    float* sF      = cF + 4194304;               // 4194304

    k_stats6<<<dim3(2048), 512, 0, stream>>>(content, style, cmean, crstd, smean);
    k_wprep<<<dim3(128, 8), 256, 0, stream>>>(w1, b1, cmean, crstd, smean,
                                              W1c, bias1c, W1s, bias1s);
    k_w2prep<<<dim3(16), 256, 0, stream>>>(w2, W2b);
    k_net_mfma<<<dim3(256, 8), 256, 0, stream>>>(content, W1c, bias1c, W2b, b2, cF, 1);
    k_net_mfma<<<dim3(256, 8), 256, 0, stream>>>(style, W1s, bias1s, W2b, b2, sF, 0);
    k_gram<<<dim3(16, 8), 256, 0, stream>>>(sF, partial);
    k_softmax<<<dim3(8), dim3(32, 32), 0, stream>>>(partial, scov);
    k_final<<<dim3(256, 8), 256, 0, stream>>>(cF, scov, wu, bu, smean, content, out);
}

// Round 10
// 246.490 us; speedup vs baseline: 1.0621x; 1.0621x over previous
//
#include <hip/hip_runtime.h>

#define HW 16384
#define C_IN 256
#define C_MID 128
#define C_OUT 32
#define EPSF 1e-5f

typedef __bf16 bf16x8 __attribute__((ext_vector_type(8)));
typedef __bf16 bf16x4 __attribute__((ext_vector_type(4)));
typedef float f32x4 __attribute__((ext_vector_type(4)));

// ---------------- Kernel 1: stats. content=allocating (keep L3-resident),
// style=NT (stream at NT rate, don't evict content). ----------
__global__ __launch_bounds__(512) void k_stats7(const float* __restrict__ content,
                                                const float* __restrict__ style,
                                                float* __restrict__ cmean,
                                                float* __restrict__ crstd,
                                                float* __restrict__ smean) {
    const int bc = blockIdx.x;          // 0..2047
    const int t = threadIdx.x;          // 0..511
    const f32x4* cp = (const f32x4*)(content + (size_t)bc * HW);
    const f32x4* sp = (const f32x4*)(style + (size_t)bc * HW);
    const int phase = (bc * 257) & 4095;

    f32x4 c0 = cp[(phase + t          ) & 4095];
    f32x4 c1 = cp[(phase + t +  1*512) & 4095];
    f32x4 c2 = cp[(phase + t +  2*512) & 4095];
    f32x4 c3 = cp[(phase + t +  3*512) & 4095];
    f32x4 c4 = cp[(phase + t +  4*512) & 4095];
    f32x4 c5 = cp[(phase + t +  5*512) & 4095];
    f32x4 c6 = cp[(phase + t +  6*512) & 4095];
    f32x4 c7 = cp[(phase + t +  7*512) & 4095];
    f32x4 s0 = __builtin_nontemporal_load(sp + ((phase + t          ) & 4095));
    f32x4 s1 = __builtin_nontemporal_load(sp + ((phase + t +  1*512) & 4095));
    f32x4 s2 = __builtin_nontemporal_load(sp + ((phase + t +  2*512) & 4095));
    f32x4 s3 = __builtin_nontemporal_load(sp + ((phase + t +  3*512) & 4095));
    f32x4 s4 = __builtin_nontemporal_load(sp + ((phase + t +  4*512) & 4095));
    f32x4 s5 = __builtin_nontemporal_load(sp + ((phase + t +  5*512) & 4095));
    f32x4 s6 = __builtin_nontemporal_load(sp + ((phase + t +  6*512) & 4095));
    f32x4 s7 = __builtin_nontemporal_load(sp + ((phase + t +  7*512) & 4095));
    asm volatile("" ::
        "v"(c0), "v"(c1), "v"(c2), "v"(c3), "v"(c4), "v"(c5), "v"(c6), "v"(c7),
        "v"(s0), "v"(s1), "v"(s2), "v"(s3), "v"(s4), "v"(s5), "v"(s6), "v"(s7));

    float cs, cq, ss;
    {
        f32x4 a01 = c0 + c1, a23 = c2 + c3, a45 = c4 + c5, a67 = c6 + c7;
        f32x4 a = (a01 + a23) + (a45 + a67);
        cs = (a[0] + a[1]) + (a[2] + a[3]);
        f32x4 q01 = c0 * c0 + c1 * c1, q23 = c2 * c2 + c3 * c3;
        f32x4 q45 = c4 * c4 + c5 * c5, q67 = c6 * c6 + c7 * c7;
        f32x4 q = (q01 + q23) + (q45 + q67);
        cq = (q[0] + q[1]) + (q[2] + q[3]);
        f32x4 b01 = s0 + s1, b23 = s2 + s3, b45 = s4 + s5, b67 = s6 + s7;
        f32x4 bsum = (b01 + b23) + (b45 + b67);
        ss = (bsum[0] + bsum[1]) + (bsum[2] + bsum[3]);
    }

    #pragma unroll
    for (int d = 32; d > 0; d >>= 1) {
        cs += __shfl_xor(cs, d, 64);
        cq += __shfl_xor(cq, d, 64);
        ss += __shfl_xor(ss, d, 64);
    }
    __shared__ float rs[8], rq[8], rss[8];
    const int wv = t >> 6;
    if ((t & 63) == 0) { rs[wv] = cs; rq[wv] = cq; rss[wv] = ss; }
    __syncthreads();
    if (t == 0) {
        float S = 0.f, Q = 0.f, SS = 0.f;
        #pragma unroll
        for (int i = 0; i < 8; ++i) { S += rs[i]; Q += rq[i]; SS += rss[i]; }
        float n = (float)HW;
        float var = (Q - S * S / n) / (n - 1.f);
        cmean[bc] = S / n;
        crstd[bc] = 1.f / sqrtf(var + EPSF);
        smean[bc] = SS / n;
    }
}

// ---------------- Prep: fold norm into conv1 weights (bf16) ----------------
__global__ __launch_bounds__(256) void k_wprep(const float* __restrict__ w1,
                                               const float* __restrict__ b1,
                                               const float* __restrict__ cmean,
                                               const float* __restrict__ crstd,
                                               const float* __restrict__ smean,
                                               __bf16* __restrict__ W1c,
                                               float* __restrict__ bias1c,
                                               __bf16* __restrict__ W1s,
                                               float* __restrict__ bias1s) {
    int o = blockIdx.x, b = blockIdx.y, t = threadIdx.x;
    float w = w1[o * 256 + t];
    float r = crstd[b * 256 + t];
    float wc = w * r;
    W1c[((size_t)(b * 128 + o)) * 256 + t] = (__bf16)wc;
    if (b == 0) W1s[o * 256 + t] = (__bf16)w;
    float pc = wc * cmean[b * 256 + t];
    float ps = w * smean[b * 256 + t];
    __shared__ float rA[256], rB[256];
    rA[t] = pc; rB[t] = ps;
    __syncthreads();
    for (int off = 128; off > 0; off >>= 1) {
        if (t < off) { rA[t] += rA[t + off]; rB[t] += rB[t + off]; }
        __syncthreads();
    }
    if (t == 0) {
        bias1c[b * 128 + o] = b1[o] - rA[0];
        bias1s[b * 128 + o] = b1[o] - rB[0];
    }
}

__global__ __launch_bounds__(256) void k_w2prep(const float* __restrict__ w2,
                                                __bf16* __restrict__ W2b) {
    int i = blockIdx.x * 256 + threadIdx.x;   // 4096 total
    if (i < 4096) W2b[i] = (__bf16)w2[i];
}

template <bool NT>
__device__ __forceinline__ float ld_f32(const float* p) {
    if constexpr (NT) return __builtin_nontemporal_load(p);
    else return *p;
}

// ---------------- Kernel 2: MFMA fused net (NT_X: stream x without L3 alloc)
template <bool NT_X>
__global__ __launch_bounds__(256) void k_net_mfma(const float* __restrict__ x,
                                                  const __bf16* __restrict__ W1,
                                                  const float* __restrict__ bias1,
                                                  const __bf16* __restrict__ W2,
                                                  const float* __restrict__ b2,
                                                  float* __restrict__ outF,
                                                  int w1_per_batch) {
    __shared__ __bf16 Xl[64 * 256];   // 32 KB, [p][c] swizzled
    __shared__ __bf16 Tl[64 * 128];   // 16 KB, [p][o] swizzled
    const int tid = threadIdx.x;
    const int l = tid & 63, wv = tid >> 6;
    const int lr = l & 15, g = l >> 4;
    const int sw = (lr & 7) << 4;
    const int p0 = blockIdx.x * 64;
    const int b = blockIdx.y;
    const float* xb = x + (size_t)b * C_IN * HW;

    {
        const int p = wv * 16 + lr;
        const float* xp = xb + p0 + p;
        char* row = (char*)&Xl[p * 256];
        #pragma unroll 4
        for (int cc = 0; cc < 16; ++cc) {
            const int c = cc * 16 + g * 4;
            float f0 = ld_f32<NT_X>(xp + (size_t)(c + 0) * HW);
            float f1 = ld_f32<NT_X>(xp + (size_t)(c + 1) * HW);
            float f2 = ld_f32<NT_X>(xp + (size_t)(c + 2) * HW);
            float f3 = ld_f32<NT_X>(xp + (size_t)(c + 3) * HW);
            bf16x4 v;
            v[0] = (__bf16)f0; v[1] = (__bf16)f1; v[2] = (__bf16)f2; v[3] = (__bf16)f3;
            *(bf16x4*)(row + ((c * 2) ^ sw)) = v;
        }
    }
    __syncthreads();

    const f32x4 zero4 = {0.f, 0.f, 0.f, 0.f};
    f32x4 acc[2][4];
    #pragma unroll
    for (int mt = 0; mt < 2; ++mt)
        #pragma unroll
        for (int nt = 0; nt < 4; ++nt) acc[mt][nt] = zero4;

    const __bf16* W1b = W1 + (w1_per_batch ? ((size_t)b << 15) : 0);
    const __bf16* wrow0 = W1b + (size_t)(wv * 32 + lr) * 256 + g * 8;
    const __bf16* wrow1 = wrow0 + 16 * 256;

    #pragma unroll
    for (int kt = 0; kt < 8; ++kt) {
        bf16x8 a0 = *(const bf16x8*)(wrow0 + kt * 32);
        bf16x8 a1 = *(const bf16x8*)(wrow1 + kt * 32);
        #pragma unroll
        for (int nt = 0; nt < 4; ++nt) {
            const char* xrow = (const char*)&Xl[(nt * 16 + lr) * 256];
            bf16x8 bfr = *(const bf16x8*)(xrow + (((kt * 32 + g * 8) * 2) ^ sw));
            acc[0][nt] = __builtin_amdgcn_mfma_f32_16x16x32_bf16(a0, bfr, acc[0][nt], 0, 0, 0);
            acc[1][nt] = __builtin_amdgcn_mfma_f32_16x16x32_bf16(a1, bfr, acc[1][nt], 0, 0, 0);
        }
    }

    float4 bia[2];
    bia[0] = *(const float4*)&bias1[b * 128 + wv * 32 + g * 4];
    bia[1] = *(const float4*)&bias1[b * 128 + wv * 32 + 16 + g * 4];
    #pragma unroll
    for (int mt = 0; mt < 2; ++mt) {
        #pragma unroll
        for (int nt = 0; nt < 4; ++nt) {
            const int p = nt * 16 + lr;
            char* trow = (char*)&Tl[p * 128];
            const int ob = (wv * 32 + mt * 16 + g * 4) * 2;
            bf16x4 tv;
            tv[0] = (__bf16)fmaxf(acc[mt][nt][0] + bia[mt].x, 0.f);
            tv[1] = (__bf16)fmaxf(acc[mt][nt][1] + bia[mt].y, 0.f);
            tv[2] = (__bf16)fmaxf(acc[mt][nt][2] + bia[mt].z, 0.f);
            tv[3] = (__bf16)fmaxf(acc[mt][nt][3] + bia[mt].w, 0.f);
            *(bf16x4*)(trow + (ob ^ sw)) = tv;
        }
    }
    __syncthreads();

    f32x4 acc2[2];
    acc2[0] = zero4; acc2[1] = zero4;
    const int p = wv * 16 + lr;
    const char* trow = (const char*)&Tl[p * 128];
    const __bf16* w2r0 = W2 + (size_t)lr * 128 + g * 8;
    const __bf16* w2r1 = w2r0 + 16 * 128;
    #pragma unroll
    for (int kt = 0; kt < 4; ++kt) {
        bf16x8 bfr = *(const bf16x8*)(trow + (((kt * 32 + g * 8) * 2) ^ sw));
        bf16x8 a0 = *(const bf16x8*)(w2r0 + kt * 32);
        bf16x8 a1 = *(const bf16x8*)(w2r1 + kt * 32);
        acc2[0] = __builtin_amdgcn_mfma_f32_16x16x32_bf16(a0, bfr, acc2[0], 0, 0, 0);
        acc2[1] = __builtin_amdgcn_mfma_f32_16x16x32_bf16(a1, bfr, acc2[1], 0, 0, 0);
    }
    float4 bb0 = *(const float4*)&b2[g * 4];
    float4 bb1 = *(const float4*)&b2[16 + g * 4];
    float* ob = outF + (size_t)b * C_OUT * HW + p0 + p;
    const int o0 = g * 4;
    ob[(size_t)(o0 + 0) * HW] = acc2[0][0] + bb0.x;
    ob[(size_t)(o0 + 1) * HW] = acc2[0][1] + bb0.y;
    ob[(size_t)(o0 + 2) * HW] = acc2[0][2] + bb0.z;
    ob[(size_t)(o0 + 3) * HW] = acc2[0][3] + bb0.w;
    ob[(size_t)(16 + o0 + 0) * HW] = acc2[1][0] + bb1.x;
    ob[(size_t)(16 + o0 + 1) * HW] = acc2[1][1] + bb1.y;
    ob[(size_t)(16 + o0 + 2) * HW] = acc2[1][2] + bb1.z;
    ob[(size_t)(16 + o0 + 3) * HW] = acc2[1][3] + bb1.w;
}

// ---------------- Kernel 3: partial gram of sF ----------
__global__ __launch_bounds__(256) void k_gram(const float* __restrict__ sF,
                                              float* __restrict__ partial) {
    __shared__ float sS[32 * 257];
    int b = blockIdx.y, sl = blockIdx.x;
    int t = threadIdx.x;
    const float* base = sF + (size_t)b * C_OUT * HW + sl * 1024;
    int i = t >> 3, jb = (t & 7) * 4;
    float acc[4] = {0.f, 0.f, 0.f, 0.f};
    for (int ch = 0; ch < 4; ++ch) {
        __syncthreads();
        #pragma unroll
        for (int r = 0; r < 32; ++r)
            sS[r * 257 + t] = base[(size_t)r * HW + ch * 256 + t];
        __syncthreads();
        for (int n = 0; n < 256; ++n) {
            float si = sS[i * 257 + n];
            #pragma unroll
            for (int q = 0; q < 4; ++q)
                acc[q] = fmaf(si, sS[(jb + q) * 257 + n], acc[q]);
        }
    }
    float* dst = partial + ((size_t)(b * 16 + sl)) * 1024 + t * 4;
    #pragma unroll
    for (int q = 0; q < 4; ++q) dst[q] = acc[q];
}

// ---------------- Kernel 4: reduce partials + softmax + scale ----------
__global__ __launch_bounds__(1024) void k_softmax(const float* __restrict__ partial,
                                                  float* __restrict__ scov) {
    int b = blockIdx.x;
    int j = threadIdx.x, i = threadIdx.y;
    float v = 0.f;
    #pragma unroll
    for (int s = 0; s < 16; ++s)
        v += partial[((size_t)(b * 16 + s)) * 1024 + i * 32 + j];
    v *= (1.f / (float)HW);
    float m = v;
    #pragma unroll
    for (int d = 16; d > 0; d >>= 1) m = fmaxf(m, __shfl_xor(m, d, 32));
    float e = expf(v - m);
    float sum = e;
    #pragma unroll
    for (int d = 16; d > 0; d >>= 1) sum += __shfl_xor(sum, d, 32);
    scov[(size_t)b * 1024 + i * 32 + j] = e / sum * 0.17677669529663687f;
}

// ---------------- Kernel 5: out = wu@(scov@cF) + bu + smean + content ----
__global__ __launch_bounds__(256) void k_final(const float* __restrict__ cF,
                                               const float* __restrict__ scov,
                                               const float* __restrict__ wu,
                                               const float* __restrict__ bu,
                                               const float* __restrict__ smean,
                                               const float* __restrict__ content,
                                               float* __restrict__ out) {
    __shared__ float sCov[1024];
    __shared__ float sC[32 * 64];
    __shared__ float sG[32 * 64];
    __shared__ float sWu[32 * 260];
    int t = threadIdx.x;
    int p0 = blockIdx.x * 64;
    int b = blockIdx.y;
    #pragma unroll
    for (int q = 0; q < 4; ++q) sCov[t + 256 * q] = scov[(size_t)b * 1024 + t + 256 * q];
    {
        int p = t & 63, rb = t >> 6;
        #pragma unroll
        for (int pass = 0; pass < 8; ++pass) {
            int r = pass * 4 + rb;
            sC[r * 64 + p] = cF[(size_t)b * C_OUT * HW + (size_t)r * HW + p0 + p];
        }
    }
    {
        int k = t & 31, ob = t >> 5;
        #pragma unroll
        for (int pass = 0; pass < 32; ++pass) {
            int o = pass * 8 + ob;
            sWu[k * 260 + o] = wu[o * 32 + k];
        }
    }
    __syncthreads();
    {
        int gp = t & 63, gib = (t >> 6) * 8;
        #pragma unroll
        for (int rr = 0; rr < 8; ++rr) {
            int gi = gib + rr;
            float a = 0.f;
            #pragma unroll
            for (int k = 0; k < 32; ++k)
                a = fmaf(sCov[gi * 32 + k], sC[k * 64 + gp], a);
            sG[gi * 64 + gp] = a;
        }
    }
    __syncthreads();
    int tx = t & 7, ty = t >> 3;
    float acc[8][8];
    #pragma unroll
    for (int i = 0; i < 8; ++i)
        #pragma unroll
        for (int j = 0; j < 8; ++j) acc[i][j] = 0.f;
    #pragma unroll 4
    for (int k = 0; k < 32; ++k) {
        float4 a4a = *(const float4*)&sWu[k * 260 + ty * 8];
        float4 a4b = *(const float4*)&sWu[k * 260 + ty * 8 + 4];
        float4 b4a = *(const float4*)&sG[k * 64 + tx * 8];
        float4 b4b = *(const float4*)&sG[k * 64 + tx * 8 + 4];
        float a[8] = {a4a.x, a4a.y, a4a.z, a4a.w, a4b.x, a4b.y, a4b.z, a4b.w};
        float bb[8] = {b4a.x, b4a.y, b4a.z, b4a.w, b4b.x, b4b.y, b4b.z, b4b.w};
        #pragma unroll
        for (int i = 0; i < 8; ++i)
            #pragma unroll
            for (int j = 0; j < 8; ++j)
                acc[i][j] = fmaf(a[i], bb[j], acc[i][j]);
    }
    #pragma unroll
    for (int i = 0; i < 8; ++i) {
        int o = ty * 8 + i;
        float add = bu[o] + smean[b * 256 + o];
        const float* csrc = content + (size_t)b * C_IN * HW + (size_t)o * HW + p0 + tx * 8;
        float* dst = out + (size_t)b * C_IN * HW + (size_t)o * HW + p0 + tx * 8;
        float4 c0 = *(const float4*)csrc;
        float4 c1 = *(const float4*)(csrc + 4);
        f32x4 r0 = {acc[i][0] + add + c0.x, acc[i][1] + add + c0.y,
                    acc[i][2] + add + c0.z, acc[i][3] + add + c0.w};
        f32x4 r1 = {acc[i][4] + add + c1.x, acc[i][5] + add + c1.y,
                    acc[i][6] + add + c1.z, acc[i][7] + add + c1.w};
        __builtin_nontemporal_store(r0, (f32x4*)dst);
        __builtin_nontemporal_store(r1, (f32x4*)(dst + 4));
    }
}

extern "C" void kernel_launch(void* const* d_in, const int* in_sizes, int n_in,
                              void* d_out, int out_size, void* d_ws, size_t ws_size,
                              hipStream_t stream) {
    const float* content = (const float*)d_in[0];
    const float* style   = (const float*)d_in[1];
    const float* w1      = (const float*)d_in[2];
    const float* b1      = (const float*)d_in[3];
    const float* w2      = (const float*)d_in[4];
    const float* b2      = (const float*)d_in[5];
    const float* wu      = (const float*)d_in[6];
    const float* bu      = (const float*)d_in[7];
    float* out = (float*)d_out;
    float* ws  = (float*)d_ws;

    float* cmean   = ws;                         // 2048
    float* crstd   = ws + 2048;                  // 2048
    float* smean   = ws + 4096;                  // 2048
    float* scov    = ws + 6144;                  // 8192 (live: softmax->final)
    __bf16* W2b    = (__bf16*)(ws + 6144);       // 4096 bf16 (dead before scov written)
    float* bias1c  = ws + 8192;                  // 1024
    float* bias1s  = ws + 9216;                  // 1024
    float* partial = ws + 14336;                 // 131072 (live: gram->softmax)
    __bf16* W1c    = (__bf16*)(ws + 14336);      // 262144 bf16 (dead before partial written)
    __bf16* W1s    = (__bf16*)(ws + 145408);     // 32768 bf16
    float* cF      = ws + 161792;                // 4194304
    float* sF      = cF + 4194304;               // 4194304

    k_stats7<<<dim3(2048), 512, 0, stream>>>(content, style, cmean, crstd, smean);
    k_wprep<<<dim3(128, 8), 256, 0, stream>>>(w1, b1, cmean, crstd, smean,
                                              W1c, bias1c, W1s, bias1s);
    k_w2prep<<<dim3(16), 256, 0, stream>>>(w2, W2b);
    k_net_mfma<false><<<dim3(256, 8), 256, 0, stream>>>(content, W1c, bias1c, W2b, b2, cF, 1);
    k_net_mfma<true><<<dim3(256, 8), 256, 0, stream>>>(style, W1s, bias1s, W2b, b2, sF, 0);
    k_gram<<<dim3(16, 8), 256, 0, stream>>>(sF, partial);
    k_softmax<<<dim3(8), dim3(32, 32), 0, stream>>>(partial, scov);
    k_final<<<dim3(256, 8), 256, 0, stream>>>(cF, scov, wu, bu, smean, content, out);
}

// Round 11
// 246.303 us; speedup vs baseline: 1.0629x; 1.0008x over previous
//
#include <hip/hip_runtime.h>

#define HW 16384
#define C_IN 256
#define C_MID 128
#define C_OUT 32
#define EPSF 1e-5f

typedef __bf16 bf16x8 __attribute__((ext_vector_type(8)));
typedef __bf16 bf16x4 __attribute__((ext_vector_type(4)));
typedef float f32x4 __attribute__((ext_vector_type(4)));

__device__ __forceinline__ bf16x4 cvt4(f32x4 v) {
    bf16x4 r;
    r[0] = (__bf16)v[0]; r[1] = (__bf16)v[1];
    r[2] = (__bf16)v[2]; r[3] = (__bf16)v[3];
    return r;
}

// ---------------- Kernel 1: stats (+ optional bf16 copy pass) ----------
// MODE 0: content allocating, style NT, no copies   (round-10 behavior)
// MODE 1: both NT, write bf16 copies (allocating stores -> L3-resident)
template <int MODE>
__global__ __launch_bounds__(512) void k_stats8(const float* __restrict__ content,
                                                const float* __restrict__ style,
                                                float* __restrict__ cmean,
                                                float* __restrict__ crstd,
                                                float* __restrict__ smean,
                                                __bf16* __restrict__ cbf,
                                                __bf16* __restrict__ sbf) {
    const int bc = blockIdx.x;          // 0..2047
    const int t = threadIdx.x;          // 0..511
    const f32x4* cp = (const f32x4*)(content + (size_t)bc * HW);
    const f32x4* sp = (const f32x4*)(style + (size_t)bc * HW);
    const int phase = (bc * 257) & 4095;

    int idx[8];
    #pragma unroll
    for (int i = 0; i < 8; ++i) idx[i] = (phase + t + i * 512) & 4095;

    f32x4 c[8], s[8];
    #pragma unroll
    for (int i = 0; i < 8; ++i)
        c[i] = (MODE == 1) ? __builtin_nontemporal_load(cp + idx[i]) : cp[idx[i]];
    #pragma unroll
    for (int i = 0; i < 8; ++i)
        s[i] = __builtin_nontemporal_load(sp + idx[i]);
    asm volatile("" ::
        "v"(c[0]), "v"(c[1]), "v"(c[2]), "v"(c[3]), "v"(c[4]), "v"(c[5]), "v"(c[6]), "v"(c[7]),
        "v"(s[0]), "v"(s[1]), "v"(s[2]), "v"(s[3]), "v"(s[4]), "v"(s[5]), "v"(s[6]), "v"(s[7]));

    if constexpr (MODE == 1) {
        bf16x4* cb = (bf16x4*)(cbf + (size_t)bc * HW);
        bf16x4* sb = (bf16x4*)(sbf + (size_t)bc * HW);
        #pragma unroll
        for (int i = 0; i < 8; ++i) {
            cb[idx[i]] = cvt4(c[i]);
            sb[idx[i]] = cvt4(s[i]);
        }
    }

    float cs, cq, ss;
    {
        f32x4 a01 = c[0] + c[1], a23 = c[2] + c[3], a45 = c[4] + c[5], a67 = c[6] + c[7];
        f32x4 a = (a01 + a23) + (a45 + a67);
        cs = (a[0] + a[1]) + (a[2] + a[3]);
        f32x4 q01 = c[0]*c[0] + c[1]*c[1], q23 = c[2]*c[2] + c[3]*c[3];
        f32x4 q45 = c[4]*c[4] + c[5]*c[5], q67 = c[6]*c[6] + c[7]*c[7];
        f32x4 q = (q01 + q23) + (q45 + q67);
        cq = (q[0] + q[1]) + (q[2] + q[3]);
        f32x4 b01 = s[0] + s[1], b23 = s[2] + s[3], b45 = s[4] + s[5], b67 = s[6] + s[7];
        f32x4 bsum = (b01 + b23) + (b45 + b67);
        ss = (bsum[0] + bsum[1]) + (bsum[2] + bsum[3]);
    }

    #pragma unroll
    for (int d = 32; d > 0; d >>= 1) {
        cs += __shfl_xor(cs, d, 64);
        cq += __shfl_xor(cq, d, 64);
        ss += __shfl_xor(ss, d, 64);
    }
    __shared__ float rs[8], rq[8], rss[8];
    const int wv = t >> 6;
    if ((t & 63) == 0) { rs[wv] = cs; rq[wv] = cq; rss[wv] = ss; }
    __syncthreads();
    if (t == 0) {
        float S = 0.f, Q = 0.f, SS = 0.f;
        #pragma unroll
        for (int i = 0; i < 8; ++i) { S += rs[i]; Q += rq[i]; SS += rss[i]; }
        float n = (float)HW;
        float var = (Q - S * S / n) / (n - 1.f);
        cmean[bc] = S / n;
        crstd[bc] = 1.f / sqrtf(var + EPSF);
        smean[bc] = SS / n;
    }
}

// ---------------- Prep: fold norm into conv1 weights (bf16) ----------------
__global__ __launch_bounds__(256) void k_wprep(const float* __restrict__ w1,
                                               const float* __restrict__ b1,
                                               const float* __restrict__ cmean,
                                               const float* __restrict__ crstd,
                                               const float* __restrict__ smean,
                                               __bf16* __restrict__ W1c,
                                               float* __restrict__ bias1c,
                                               __bf16* __restrict__ W1s,
                                               float* __restrict__ bias1s) {
    int o = blockIdx.x, b = blockIdx.y, t = threadIdx.x;
    float w = w1[o * 256 + t];
    float r = crstd[b * 256 + t];
    float wc = w * r;
    W1c[((size_t)(b * 128 + o)) * 256 + t] = (__bf16)wc;
    if (b == 0) W1s[o * 256 + t] = (__bf16)w;
    float pc = wc * cmean[b * 256 + t];
    float ps = w * smean[b * 256 + t];
    __shared__ float rA[256], rB[256];
    rA[t] = pc; rB[t] = ps;
    __syncthreads();
    for (int off = 128; off > 0; off >>= 1) {
        if (t < off) { rA[t] += rA[t + off]; rB[t] += rB[t + off]; }
        __syncthreads();
    }
    if (t == 0) {
        bias1c[b * 128 + o] = b1[o] - rA[0];
        bias1s[b * 128 + o] = b1[o] - rB[0];
    }
}

__global__ __launch_bounds__(256) void k_w2prep(const float* __restrict__ w2,
                                                __bf16* __restrict__ W2b) {
    int i = blockIdx.x * 256 + threadIdx.x;   // 4096 total
    if (i < 4096) W2b[i] = (__bf16)w2[i];
}

template <bool NT>
__device__ __forceinline__ float ld_f32(const float* p) {
    if constexpr (NT) return __builtin_nontemporal_load(p);
    else return *p;
}

// ---------------- Kernel 2a: MFMA fused net, f32 input (fallback path) ----
template <bool NT_X>
__global__ __launch_bounds__(256) void k_net_mfma(const float* __restrict__ x,
                                                  const __bf16* __restrict__ W1,
                                                  const float* __restrict__ bias1,
                                                  const __bf16* __restrict__ W2,
                                                  const float* __restrict__ b2,
                                                  float* __restrict__ outF,
                                                  int w1_per_batch) {
    __shared__ __bf16 Xl[64 * 256];
    __shared__ __bf16 Tl[64 * 128];
    const int tid = threadIdx.x;
    const int l = tid & 63, wv = tid >> 6;
    const int lr = l & 15, g = l >> 4;
    const int sw = (lr & 7) << 4;
    const int p0 = blockIdx.x * 64;
    const int b = blockIdx.y;
    const float* xb = x + (size_t)b * C_IN * HW;

    {
        const int p = wv * 16 + lr;
        const float* xp = xb + p0 + p;
        char* row = (char*)&Xl[p * 256];
        #pragma unroll 4
        for (int cc = 0; cc < 16; ++cc) {
            const int c = cc * 16 + g * 4;
            float f0 = ld_f32<NT_X>(xp + (size_t)(c + 0) * HW);
            float f1 = ld_f32<NT_X>(xp + (size_t)(c + 1) * HW);
            float f2 = ld_f32<NT_X>(xp + (size_t)(c + 2) * HW);
            float f3 = ld_f32<NT_X>(xp + (size_t)(c + 3) * HW);
            bf16x4 v;
            v[0] = (__bf16)f0; v[1] = (__bf16)f1; v[2] = (__bf16)f2; v[3] = (__bf16)f3;
            *(bf16x4*)(row + ((c * 2) ^ sw)) = v;
        }
    }
    __syncthreads();

    const f32x4 zero4 = {0.f, 0.f, 0.f, 0.f};
    f32x4 acc[2][4];
    #pragma unroll
    for (int mt = 0; mt < 2; ++mt)
        #pragma unroll
        for (int nt = 0; nt < 4; ++nt) acc[mt][nt] = zero4;

    const __bf16* W1b = W1 + (w1_per_batch ? ((size_t)b << 15) : 0);
    const __bf16* wrow0 = W1b + (size_t)(wv * 32 + lr) * 256 + g * 8;
    const __bf16* wrow1 = wrow0 + 16 * 256;

    #pragma unroll
    for (int kt = 0; kt < 8; ++kt) {
        bf16x8 a0 = *(const bf16x8*)(wrow0 + kt * 32);
        bf16x8 a1 = *(const bf16x8*)(wrow1 + kt * 32);
        #pragma unroll
        for (int nt = 0; nt < 4; ++nt) {
            const char* xrow = (const char*)&Xl[(nt * 16 + lr) * 256];
            bf16x8 bfr = *(const bf16x8*)(xrow + (((kt * 32 + g * 8) * 2) ^ sw));
            acc[0][nt] = __builtin_amdgcn_mfma_f32_16x16x32_bf16(a0, bfr, acc[0][nt], 0, 0, 0);
            acc[1][nt] = __builtin_amdgcn_mfma_f32_16x16x32_bf16(a1, bfr, acc[1][nt], 0, 0, 0);
        }
    }

    float4 bia[2];
    bia[0] = *(const float4*)&bias1[b * 128 + wv * 32 + g * 4];
    bia[1] = *(const float4*)&bias1[b * 128 + wv * 32 + 16 + g * 4];
    #pragma unroll
    for (int mt = 0; mt < 2; ++mt) {
        #pragma unroll
        for (int nt = 0; nt < 4; ++nt) {
            const int p = nt * 16 + lr;
            char* trow = (char*)&Tl[p * 128];
            const int ob = (wv * 32 + mt * 16 + g * 4) * 2;
            bf16x4 tv;
            tv[0] = (__bf16)fmaxf(acc[mt][nt][0] + bia[mt].x, 0.f);
            tv[1] = (__bf16)fmaxf(acc[mt][nt][1] + bia[mt].y, 0.f);
            tv[2] = (__bf16)fmaxf(acc[mt][nt][2] + bia[mt].z, 0.f);
            tv[3] = (__bf16)fmaxf(acc[mt][nt][3] + bia[mt].w, 0.f);
            *(bf16x4*)(trow + (ob ^ sw)) = tv;
        }
    }
    __syncthreads();

    f32x4 acc2[2];
    acc2[0] = zero4; acc2[1] = zero4;
    const int p = wv * 16 + lr;
    const char* trow = (const char*)&Tl[p * 128];
    const __bf16* w2r0 = W2 + (size_t)lr * 128 + g * 8;
    const __bf16* w2r1 = w2r0 + 16 * 128;
    #pragma unroll
    for (int kt = 0; kt < 4; ++kt) {
        bf16x8 bfr = *(const bf16x8*)(trow + (((kt * 32 + g * 8) * 2) ^ sw));
        bf16x8 a0 = *(const bf16x8*)(w2r0 + kt * 32);
        bf16x8 a1 = *(const bf16x8*)(w2r1 + kt * 32);
        acc2[0] = __builtin_amdgcn_mfma_f32_16x16x32_bf16(a0, bfr, acc2[0], 0, 0, 0);
        acc2[1] = __builtin_amdgcn_mfma_f32_16x16x32_bf16(a1, bfr, acc2[1], 0, 0, 0);
    }
    float4 bb0 = *(const float4*)&b2[g * 4];
    float4 bb1 = *(const float4*)&b2[16 + g * 4];
    float* ob = outF + (size_t)b * C_OUT * HW + p0 + p;
    const int o0 = g * 4;
    ob[(size_t)(o0 + 0) * HW] = acc2[0][0] + bb0.x;
    ob[(size_t)(o0 + 1) * HW] = acc2[0][1] + bb0.y;
    ob[(size_t)(o0 + 2) * HW] = acc2[0][2] + bb0.z;
    ob[(size_t)(o0 + 3) * HW] = acc2[0][3] + bb0.w;
    ob[(size_t)(16 + o0 + 0) * HW] = acc2[1][0] + bb1.x;
    ob[(size_t)(16 + o0 + 1) * HW] = acc2[1][1] + bb1.y;
    ob[(size_t)(16 + o0 + 2) * HW] = acc2[1][2] + bb1.z;
    ob[(size_t)(16 + o0 + 3) * HW] = acc2[1][3] + bb1.w;
}

// ---------------- Kernel 2b: MFMA fused net, bf16 input (L3-resident copy) --
__global__ __launch_bounds__(256) void k_net_mfma_bf(const __bf16* __restrict__ x,
                                                     const __bf16* __restrict__ W1,
                                                     const float* __restrict__ bias1,
                                                     const __bf16* __restrict__ W2,
                                                     const float* __restrict__ b2,
                                                     float* __restrict__ outF,
                                                     int w1_per_batch) {
    __shared__ __bf16 Xl[64 * 256];
    __shared__ __bf16 Tl[64 * 128];
    const int tid = threadIdx.x;
    const int l = tid & 63, wv = tid >> 6;
    const int lr = l & 15, g = l >> 4;
    const int sw = (lr & 7) << 4;
    const int p0 = blockIdx.x * 64;
    const int b = blockIdx.y;
    const __bf16* xb = x + (size_t)b * C_IN * HW;

    {
        const int p = wv * 16 + lr;
        const __bf16* xp = xb + p0 + p;
        char* row = (char*)&Xl[p * 256];
        #pragma unroll 4
        for (int cc = 0; cc < 16; ++cc) {
            const int c = cc * 16 + g * 4;
            bf16x4 v;
            v[0] = xp[(size_t)(c + 0) * HW];
            v[1] = xp[(size_t)(c + 1) * HW];
            v[2] = xp[(size_t)(c + 2) * HW];
            v[3] = xp[(size_t)(c + 3) * HW];
            *(bf16x4*)(row + ((c * 2) ^ sw)) = v;
        }
    }
    __syncthreads();

    const f32x4 zero4 = {0.f, 0.f, 0.f, 0.f};
    f32x4 acc[2][4];
    #pragma unroll
    for (int mt = 0; mt < 2; ++mt)
        #pragma unroll
        for (int nt = 0; nt < 4; ++nt) acc[mt][nt] = zero4;

    const __bf16* W1b = W1 + (w1_per_batch ? ((size_t)b << 15) : 0);
    const __bf16* wrow0 = W1b + (size_t)(wv * 32 + lr) * 256 + g * 8;
    const __bf16* wrow1 = wrow0 + 16 * 256;

    #pragma unroll
    for (int kt = 0; kt < 8; ++kt) {
        bf16x8 a0 = *(const bf16x8*)(wrow0 + kt * 32);
        bf16x8 a1 = *(const bf16x8*)(wrow1 + kt * 32);
        #pragma unroll
        for (int nt = 0; nt < 4; ++nt) {
            const char* xrow = (const char*)&Xl[(nt * 16 + lr) * 256];
            bf16x8 bfr = *(const bf16x8*)(xrow + (((kt * 32 + g * 8) * 2) ^ sw));
            acc[0][nt] = __builtin_amdgcn_mfma_f32_16x16x32_bf16(a0, bfr, acc[0][nt], 0, 0, 0);
            acc[1][nt] = __builtin_amdgcn_mfma_f32_16x16x32_bf16(a1, bfr, acc[1][nt], 0, 0, 0);
        }
    }

    float4 bia[2];
    bia[0] = *(const float4*)&bias1[b * 128 + wv * 32 + g * 4];
    bia[1] = *(const float4*)&bias1[b * 128 + wv * 32 + 16 + g * 4];
    #pragma unroll
    for (int mt = 0; mt < 2; ++mt) {
        #pragma unroll
        for (int nt = 0; nt < 4; ++nt) {
            const int p = nt * 16 + lr;
            char* trow = (char*)&Tl[p * 128];
            const int ob = (wv * 32 + mt * 16 + g * 4) * 2;
            bf16x4 tv;
            tv[0] = (__bf16)fmaxf(acc[mt][nt][0] + bia[mt].x, 0.f);
            tv[1] = (__bf16)fmaxf(acc[mt][nt][1] + bia[mt].y, 0.f);
            tv[2] = (__bf16)fmaxf(acc[mt][nt][2] + bia[mt].z, 0.f);
            tv[3] = (__bf16)fmaxf(acc[mt][nt][3] + bia[mt].w, 0.f);
            *(bf16x4*)(trow + (ob ^ sw)) = tv;
        }
    }
    __syncthreads();

    f32x4 acc2[2];
    acc2[0] = zero4; acc2[1] = zero4;
    const int p = wv * 16 + lr;
    const char* trow = (const char*)&Tl[p * 128];
    const __bf16* w2r0 = W2 + (size_t)lr * 128 + g * 8;
    const __bf16* w2r1 = w2r0 + 16 * 128;
    #pragma unroll
    for (int kt = 0; kt < 4; ++kt) {
        bf16x8 bfr = *(const bf16x8*)(trow + (((kt * 32 + g * 8) * 2) ^ sw));
        bf16x8 a0 = *(const bf16x8*)(w2r0 + kt * 32);
        bf16x8 a1 = *(const bf16x8*)(w2r1 + kt * 32);
        acc2[0] = __builtin_amdgcn_mfma_f32_16x16x32_bf16(a0, bfr, acc2[0], 0, 0, 0);
        acc2[1] = __builtin_amdgcn_mfma_f32_16x16x32_bf16(a1, bfr, acc2[1], 0, 0, 0);
    }
    float4 bb0 = *(const float4*)&b2[g * 4];
    float4 bb1 = *(const float4*)&b2[16 + g * 4];
    float* ob = outF + (size_t)b * C_OUT * HW + p0 + p;
    const int o0 = g * 4;
    ob[(size_t)(o0 + 0) * HW] = acc2[0][0] + bb0.x;
    ob[(size_t)(o0 + 1) * HW] = acc2[0][1] + bb0.y;
    ob[(size_t)(o0 + 2) * HW] = acc2[0][2] + bb0.z;
    ob[(size_t)(o0 + 3) * HW] = acc2[0][3] + bb0.w;
    ob[(size_t)(16 + o0 + 0) * HW] = acc2[1][0] + bb1.x;
    ob[(size_t)(16 + o0 + 1) * HW] = acc2[1][1] + bb1.y;
    ob[(size_t)(16 + o0 + 2) * HW] = acc2[1][2] + bb1.z;
    ob[(size_t)(16 + o0 + 3) * HW] = acc2[1][3] + bb1.w;
}

// ---------------- Kernel 3: partial gram of sF ----------
__global__ __launch_bounds__(256) void k_gram(const float* __restrict__ sF,
                                              float* __restrict__ partial) {
    __shared__ float sS[32 * 257];
    int b = blockIdx.y, sl = blockIdx.x;
    int t = threadIdx.x;
    const float* base = sF + (size_t)b * C_OUT * HW + sl * 1024;
    int i = t >> 3, jb = (t & 7) * 4;
    float acc[4] = {0.f, 0.f, 0.f, 0.f};
    for (int ch = 0; ch < 4; ++ch) {
        __syncthreads();
        #pragma unroll
        for (int r = 0; r < 32; ++r)
            sS[r * 257 + t] = base[(size_t)r * HW + ch * 256 + t];
        __syncthreads();
        for (int n = 0; n < 256; ++n) {
            float si = sS[i * 257 + n];
            #pragma unroll
            for (int q = 0; q < 4; ++q)
                acc[q] = fmaf(si, sS[(jb + q) * 257 + n], acc[q]);
        }
    }
    float* dst = partial + ((size_t)(b * 16 + sl)) * 1024 + t * 4;
    #pragma unroll
    for (int q = 0; q < 4; ++q) dst[q] = acc[q];
}

// ---------------- Kernel 4: reduce partials + softmax + scale ----------
__global__ __launch_bounds__(1024) void k_softmax(const float* __restrict__ partial,
                                                  float* __restrict__ scov) {
    int b = blockIdx.x;
    int j = threadIdx.x, i = threadIdx.y;
    float v = 0.f;
    #pragma unroll
    for (int s = 0; s < 16; ++s)
        v += partial[((size_t)(b * 16 + s)) * 1024 + i * 32 + j];
    v *= (1.f / (float)HW);
    float m = v;
    #pragma unroll
    for (int d = 16; d > 0; d >>= 1) m = fmaxf(m, __shfl_xor(m, d, 32));
    float e = expf(v - m);
    float sum = e;
    #pragma unroll
    for (int d = 16; d > 0; d >>= 1) sum += __shfl_xor(sum, d, 32);
    scov[(size_t)b * 1024 + i * 32 + j] = e / sum * 0.17677669529663687f;
}

// ---------------- Kernel 5: out = wu@(scov@cF) + bu + smean + content ----
// CONTENT_BF16: residual read from the bf16 copy (L3-resident), else f32 input
template <bool CONTENT_BF16>
__global__ __launch_bounds__(256) void k_final(const float* __restrict__ cF,
                                               const float* __restrict__ scov,
                                               const float* __restrict__ wu,
                                               const float* __restrict__ bu,
                                               const float* __restrict__ smean,
                                               const float* __restrict__ content,
                                               const __bf16* __restrict__ cbf,
                                               float* __restrict__ out) {
    __shared__ float sCov[1024];
    __shared__ float sC[32 * 64];
    __shared__ float sG[32 * 64];
    __shared__ float sWu[32 * 260];
    int t = threadIdx.x;
    int p0 = blockIdx.x * 64;
    int b = blockIdx.y;
    #pragma unroll
    for (int q = 0; q < 4; ++q) sCov[t + 256 * q] = scov[(size_t)b * 1024 + t + 256 * q];
    {
        int p = t & 63, rb = t >> 6;
        #pragma unroll
        for (int pass = 0; pass < 8; ++pass) {
            int r = pass * 4 + rb;
            sC[r * 64 + p] = cF[(size_t)b * C_OUT * HW + (size_t)r * HW + p0 + p];
        }
    }
    {
        int k = t & 31, ob = t >> 5;
        #pragma unroll
        for (int pass = 0; pass < 32; ++pass) {
            int o = pass * 8 + ob;
            sWu[k * 260 + o] = wu[o * 32 + k];
        }
    }
    __syncthreads();
    {
        int gp = t & 63, gib = (t >> 6) * 8;
        #pragma unroll
        for (int rr = 0; rr < 8; ++rr) {
            int gi = gib + rr;
            float a = 0.f;
            #pragma unroll
            for (int k = 0; k < 32; ++k)
                a = fmaf(sCov[gi * 32 + k], sC[k * 64 + gp], a);
            sG[gi * 64 + gp] = a;
        }
    }
    __syncthreads();
    int tx = t & 7, ty = t >> 3;
    float acc[8][8];
    #pragma unroll
    for (int i = 0; i < 8; ++i)
        #pragma unroll
        for (int j = 0; j < 8; ++j) acc[i][j] = 0.f;
    #pragma unroll 4
    for (int k = 0; k < 32; ++k) {
        float4 a4a = *(const float4*)&sWu[k * 260 + ty * 8];
        float4 a4b = *(const float4*)&sWu[k * 260 + ty * 8 + 4];
        float4 b4a = *(const float4*)&sG[k * 64 + tx * 8];
        float4 b4b = *(const float4*)&sG[k * 64 + tx * 8 + 4];
        float a[8] = {a4a.x, a4a.y, a4a.z, a4a.w, a4b.x, a4b.y, a4b.z, a4b.w};
        float bb[8] = {b4a.x, b4a.y, b4a.z, b4a.w, b4b.x, b4b.y, b4b.z, b4b.w};
        #pragma unroll
        for (int i = 0; i < 8; ++i)
            #pragma unroll
            for (int j = 0; j < 8; ++j)
                acc[i][j] = fmaf(a[i], bb[j], acc[i][j]);
    }
    #pragma unroll
    for (int i = 0; i < 8; ++i) {
        int o = ty * 8 + i;
        float add = bu[o] + smean[b * 256 + o];
        float* dst = out + (size_t)b * C_IN * HW + (size_t)o * HW + p0 + tx * 8;
        float cv[8];
        if constexpr (CONTENT_BF16) {
            const __bf16* csrc = cbf + (size_t)b * C_IN * HW + (size_t)o * HW + p0 + tx * 8;
            bf16x8 cvv = *(const bf16x8*)csrc;
            #pragma unroll
            for (int q = 0; q < 8; ++q) cv[q] = (float)cvv[q];
        } else {
            const float* csrc = content + (size_t)b * C_IN * HW + (size_t)o * HW + p0 + tx * 8;
            float4 c0 = *(const float4*)csrc;
            float4 c1 = *(const float4*)(csrc + 4);
            cv[0] = c0.x; cv[1] = c0.y; cv[2] = c0.z; cv[3] = c0.w;
            cv[4] = c1.x; cv[5] = c1.y; cv[6] = c1.z; cv[7] = c1.w;
        }
        f32x4 r0 = {acc[i][0] + add + cv[0], acc[i][1] + add + cv[1],
                    acc[i][2] + add + cv[2], acc[i][3] + add + cv[3]};
        f32x4 r1 = {acc[i][4] + add + cv[4], acc[i][5] + add + cv[5],
                    acc[i][6] + add + cv[6], acc[i][7] + add + cv[7]};
        __builtin_nontemporal_store(r0, (f32x4*)dst);
        __builtin_nontemporal_store(r1, (f32x4*)(dst + 4));
    }
}

extern "C" void kernel_launch(void* const* d_in, const int* in_sizes, int n_in,
                              void* d_out, int out_size, void* d_ws, size_t ws_size,
                              hipStream_t stream) {
    const float* content = (const float*)d_in[0];
    const float* style   = (const float*)d_in[1];
    const float* w1      = (const float*)d_in[2];
    const float* b1      = (const float*)d_in[3];
    const float* w2      = (const float*)d_in[4];
    const float* b2      = (const float*)d_in[5];
    const float* wu      = (const float*)d_in[6];
    const float* bu      = (const float*)d_in[7];
    float* out = (float*)d_out;
    float* ws  = (float*)d_ws;

    const size_t NEED = 42240000ull * sizeof(float);   // ~169 MB
    if (ws_size >= NEED) {
        // ---- bf16-copy pipeline: inputs read from HBM exactly once ----
        float* cmean   = ws;                    // 2048
        float* crstd   = ws + 2048;             // 2048
        float* smean   = ws + 4096;             // 2048
        float* scov    = ws + 6144;             // 8192
        float* bias1c  = ws + 14336;            // 1024
        float* bias1s  = ws + 15360;            // 1024
        __bf16* W2b    = (__bf16*)(ws + 16384); // 4096 bf16
        __bf16* W1s    = (__bf16*)(ws + 18432); // 32768 bf16
        __bf16* W1c    = (__bf16*)(ws + 34816); // 262144 bf16
        float* partial = ws + 165888;           // 131072
        float* cF      = ws + 296960;           // 4194304
        float* sF      = cF + 4194304;          // 4194304
        __bf16* cbf    = (__bf16*)(ws + 8685568);            // 33554432 bf16
        __bf16* sbf    = (__bf16*)(ws + 8685568 + 16777216); // 33554432 bf16

        k_stats8<1><<<dim3(2048), 512, 0, stream>>>(content, style, cmean, crstd, smean, cbf, sbf);
        k_wprep<<<dim3(128, 8), 256, 0, stream>>>(w1, b1, cmean, crstd, smean,
                                                  W1c, bias1c, W1s, bias1s);
        k_w2prep<<<dim3(16), 256, 0, stream>>>(w2, W2b);
        k_net_mfma_bf<<<dim3(256, 8), 256, 0, stream>>>(cbf, W1c, bias1c, W2b, b2, cF, 1);
        k_net_mfma_bf<<<dim3(256, 8), 256, 0, stream>>>(sbf, W1s, bias1s, W2b, b2, sF, 0);
        k_gram<<<dim3(16, 8), 256, 0, stream>>>(sF, partial);
        k_softmax<<<dim3(8), dim3(32, 32), 0, stream>>>(partial, scov);
        k_final<true><<<dim3(256, 8), 256, 0, stream>>>(cF, scov, wu, bu, smean,
                                                        content, cbf, out);
    } else {
        // ---- fallback: exact round-10 pipeline / layout ----
        float* cmean   = ws;                         // 2048
        float* crstd   = ws + 2048;                  // 2048
        float* smean   = ws + 4096;                  // 2048
        float* scov    = ws + 6144;                  // 8192
        __bf16* W2b    = (__bf16*)(ws + 6144);       // aliases scov (dead before scov)
        float* bias1c  = ws + 8192;                  // 1024
        float* bias1s  = ws + 9216;                  // 1024
        float* partial = ws + 14336;                 // 131072
        __bf16* W1c    = (__bf16*)(ws + 14336);      // aliases partial (dead before)
        __bf16* W1s    = (__bf16*)(ws + 145408);     // 32768 bf16
        float* cF      = ws + 161792;                // 4194304
        float* sF      = cF + 4194304;               // 4194304

        k_stats8<0><<<dim3(2048), 512, 0, stream>>>(content, style, cmean, crstd, smean,
                                                    nullptr, nullptr);
        k_wprep<<<dim3(128, 8), 256, 0, stream>>>(w1, b1, cmean, crstd, smean,
                                                  W1c, bias1c, W1s, bias1s);
        k_w2prep<<<dim3(16), 256, 0, stream>>>(w2, W2b);
        k_net_mfma<false><<<dim3(256, 8), 256, 0, stream>>>(content, W1c, bias1c, W2b, b2, cF, 1);
        k_net_mfma<true><<<dim3(256, 8), 256, 0, stream>>>(style, W1s, bias1s, W2b, b2, sF, 0);
        k_gram<<<dim3(16, 8), 256, 0, stream>>>(sF, partial);
        k_softmax<<<dim3(8), dim3(32, 32), 0, stream>>>(partial, scov);
        k_final<false><<<dim3(256, 8), 256, 0, stream>>>(cF, scov, wu, bu, smean,
                                                         content, nullptr, out);
    }
}